// Round 17
// baseline (1080.562 us; speedup 1.0000x reference)
//
#include <hip/hip_runtime.h>
#include <hip/hip_fp16.h>
#include <float.h>

#define NEG 0.2f
#define NPART 16
#define PAD 32   // row stride = 128B (one line); deg ~ Poisson(6), P(>=32) ~ 1e-15

typedef _Float16 half2v __attribute__((ext_vector_type(2)));

__device__ __forceinline__ float lrelu(float x){ return x > 0.f ? x : NEG * x; }
__device__ __forceinline__ float elu1(float x){ return x > 0.f ? x : (__expf(x) - 1.f); }

// ---- Padded-CSR build + per-graph node counts (fused) ----
// cur[] pre-zeroed; after this pass cur[node] == in-degree
__global__ void k_scat(const int* __restrict__ ei, const int* __restrict__ batch,
                       int* __restrict__ cur, int* __restrict__ csr_src,
                       float* __restrict__ gcnt, int N, int E){
  __shared__ float gc[128];
  int tid = threadIdx.x;
  bool doh = blockIdx.x < 256;                         // block-uniform
  if (doh && tid < 128) gc[tid] = 0.f;
  __syncthreads();
  int idx = blockIdx.x * 256 + tid;
  int gstr = gridDim.x * 256;
  for (int e = idx; e < E; e += gstr){
    int s = ei[e], d = ei[E + e];
    int pos = atomicAdd(cur + d, 1);
    if (pos < PAD) csr_src[(size_t)d * PAD + pos] = s; // guard impossible overflow
  }
  if (doh){
    for (int n = idx; n < N; n += 256 * 256)
      atomicAdd(&gc[batch[n]], 1.f);
    __syncthreads();
    if (tid < 128 && gc[tid] != 0.f) atomicAdd(gcnt + tid, gc[tid]);
  }
}

// ---- Fused layer 1: edge accumulation (linearity trick) + out1 + h2 + L2 logits
// phase 1: 8 lanes/node; first-round loads (deg, csr word, x rows) hoisted above
//          the PQ preamble -> dependent-chain depth 3->2, overlapped with barrier.
// phase 2: out1 f16 in LDS; GEMV via v_dot2_f32_f16 (W2 in 32 packed half2 regs)
// NOTE: min-waves 6 (not 8): 8 forces a 64-VGPR budget -> scratch spill (R15).
__global__ void __launch_bounds__(256, 6)
k_layer1(const int* __restrict__ degp, const int* __restrict__ csr_src,
         const float* __restrict__ x, const float* __restrict__ W1,
         const float* __restrict__ as1, const float* __restrict__ ad1,
         const float* __restrict__ b1, const float* __restrict__ W2,
         const float* __restrict__ as2, const float* __restrict__ ad2,
         __half* __restrict__ h2h, float* __restrict__ als2,
         float* __restrict__ ald2, int N){
  __shared__ float PQ[2][16];                          // [which][k*4+h]
  __shared__ __align__(16) float xa[32][20];           // per-node {acc[16], ss[4]}
  __shared__ __align__(16) _Float16 rowsh[4][128];     // per-wave out1 (f16)
  __shared__ float als_s[32], ald_s[32];               // staged L2-logit outputs
  int tid = threadIdx.x;
  const float4* x4 = (const float4*)x;

  // ---- speculative first-round loads (before PQ compute + barrier) ----
  int g1 = tid >> 3, l = tid & 7;
  int node1 = blockIdx.x * 32 + g1;
  int nd = node1 < N ? node1 : N - 1;
  int deg = degp[nd];                                  // load A
  size_t r0 = (size_t)nd * PAD;
  int s_pre = csr_src[r0 + l];                         // load B (indep of A)
  int total = (node1 < N) ? deg + 1 : 0;
  int s0 = (l < deg) ? s_pre : nd;                     // sanitize poison beyond deg
  float4 xv0 = x4[s0];                                 // gather (depth 2)
  float4 xn = x4[nd];

  if (tid < 32){
    int which = tid >> 4, kh = tid & 15, k = kh >> 2, h = kh & 3;
    const float* a = which ? ad1 : as1;
    float s = 0.f;
    #pragma unroll 8
    for (int c = 0; c < 32; c++) s += W1[k*128 + h*32 + c] * a[h*32 + c];
    PQ[which][kh] = s;
  }
  __syncthreads();

  // ---- phase 1: 8 lanes per node ----
  {
    float P[16], Q[16];
    #pragma unroll
    for (int i = 0; i < 16; i++){ P[i] = PQ[0][i]; Q[i] = PQ[1][i]; }
    float ald0 = xn.x*Q[0] + xn.y*Q[4] + xn.z*Q[8]  + xn.w*Q[12];
    float ald1_ = xn.x*Q[1] + xn.y*Q[5] + xn.z*Q[9]  + xn.w*Q[13];
    float ald2_ = xn.x*Q[2] + xn.y*Q[6] + xn.z*Q[10] + xn.w*Q[14];
    float ald3 = xn.x*Q[3] + xn.y*Q[7] + xn.z*Q[11] + xn.w*Q[15];
    float acc[16];
    #pragma unroll
    for (int i = 0; i < 16; i++) acc[i] = 0.f;
    float ss[4] = {0.f, 0.f, 0.f, 0.f};
    if (l < total){                                    // first round: preloaded
      float4 xv = xv0;
      float a0 = xv.x*P[0] + xv.y*P[4] + xv.z*P[8]  + xv.w*P[12];
      float a1 = xv.x*P[1] + xv.y*P[5] + xv.z*P[9]  + xv.w*P[13];
      float a2 = xv.x*P[2] + xv.y*P[6] + xv.z*P[10] + xv.w*P[14];
      float a3 = xv.x*P[3] + xv.y*P[7] + xv.z*P[11] + xv.w*P[15];
      float e0 = __expf(lrelu(a0 + ald0));
      float e1 = __expf(lrelu(a1 + ald1_));
      float e2 = __expf(lrelu(a2 + ald2_));
      float e3 = __expf(lrelu(a3 + ald3));
      ss[0] += e0; ss[1] += e1; ss[2] += e2; ss[3] += e3;
      acc[0]  += e0*xv.x; acc[1]  += e0*xv.y; acc[2]  += e0*xv.z; acc[3]  += e0*xv.w;
      acc[4]  += e1*xv.x; acc[5]  += e1*xv.y; acc[6]  += e1*xv.z; acc[7]  += e1*xv.w;
      acc[8]  += e2*xv.x; acc[9]  += e2*xv.y; acc[10] += e2*xv.z; acc[11] += e2*xv.w;
      acc[12] += e3*xv.x; acc[13] += e3*xv.y; acc[14] += e3*xv.z; acc[15] += e3*xv.w;
    }
    for (int t = l + 8; t < total; t += 8){            // rare (P(deg>=8) ~ 0.26)
      int s = (t < deg) ? csr_src[r0 + t] : nd;
      float4 xv = x4[s];
      float a0 = xv.x*P[0] + xv.y*P[4] + xv.z*P[8]  + xv.w*P[12];
      float a1 = xv.x*P[1] + xv.y*P[5] + xv.z*P[9]  + xv.w*P[13];
      float a2 = xv.x*P[2] + xv.y*P[6] + xv.z*P[10] + xv.w*P[14];
      float a3 = xv.x*P[3] + xv.y*P[7] + xv.z*P[11] + xv.w*P[15];
      float e0 = __expf(lrelu(a0 + ald0));
      float e1 = __expf(lrelu(a1 + ald1_));
      float e2 = __expf(lrelu(a2 + ald2_));
      float e3 = __expf(lrelu(a3 + ald3));
      ss[0] += e0; ss[1] += e1; ss[2] += e2; ss[3] += e3;
      acc[0]  += e0*xv.x; acc[1]  += e0*xv.y; acc[2]  += e0*xv.z; acc[3]  += e0*xv.w;
      acc[4]  += e1*xv.x; acc[5]  += e1*xv.y; acc[6]  += e1*xv.z; acc[7]  += e1*xv.w;
      acc[8]  += e2*xv.x; acc[9]  += e2*xv.y; acc[10] += e2*xv.z; acc[11] += e2*xv.w;
      acc[12] += e3*xv.x; acc[13] += e3*xv.y; acc[14] += e3*xv.z; acc[15] += e3*xv.w;
    }
    #pragma unroll
    for (int m = 4; m >= 1; m >>= 1){
      #pragma unroll
      for (int i = 0; i < 16; i++) acc[i] += __shfl_xor(acc[i], m, 8);
      #pragma unroll
      for (int i = 0; i < 4; i++)  ss[i]  += __shfl_xor(ss[i], m, 8);
    }
    if (l == 0){
      float* o = xa[g1];
      *(float4*)(o)      = make_float4(acc[0],  acc[1],  acc[2],  acc[3]);
      *(float4*)(o + 4)  = make_float4(acc[4],  acc[5],  acc[6],  acc[7]);
      *(float4*)(o + 8)  = make_float4(acc[8],  acc[9],  acc[10], acc[11]);
      *(float4*)(o + 12) = make_float4(acc[12], acc[13], acc[14], acc[15]);
      *(float4*)(o + 16) = make_float4(ss[0], ss[1], ss[2], ss[3]);
    }
  }
  __syncthreads();
  __builtin_amdgcn_sched_barrier(0);   // keep phase-2 weight loads below phase 1

  // ---- phase-2 constants: live range starts after phase 1 (no spill) ----
  int L = tid & 63, w = tid >> 6;
  int half = L >> 5, c = L & 31;
  half2v w2h[32];
  #pragma unroll
  for (int kk = 0; kk < 32; kk++){
    half2v t;
    t.x = (_Float16)W2[(half*64 + 2*kk)*32 + c];
    t.y = (_Float16)W2[(half*64 + 2*kk + 1)*32 + c];
    w2h[kk] = t;
  }
  float w1a[4], w1b[4];
  #pragma unroll
  for (int k = 0; k < 4; k++){ w1a[k] = W1[k*128 + L]; w1b[k] = W1[k*128 + 64 + L]; }
  float b1a = b1[L], b1b = b1[64 + L];
  float asc = as2[c], adc = ad2[c];
  int ha = L >> 5, hb = 2 + (L >> 5);
  _Float16* rwh = rowsh[w];

  // ---- phase 2: each wave handles 8 nodes; GEMV via fdot2 ----
  for (int i = 0; i < 8; i++){
    int g = w*8 + i;
    int node = blockIdx.x * 32 + g;
    if (node >= N) continue;                           // wave-uniform
    const float* xg = xa[g];
    float4 xva = *(const float4*)(xg + ha*4);          // broadcast LDS
    float4 xvb = *(const float4*)(xg + hb*4);
    float ssa = xg[16 + ha], ssb = xg[16 + hb];
    float oa = elu1((xva.x*w1a[0] + xva.y*w1a[1] + xva.z*w1a[2] + xva.w*w1a[3]) / ssa + b1a);
    float ob = elu1((xvb.x*w1b[0] + xvb.y*w1b[1] + xvb.z*w1b[2] + xvb.w*w1b[3]) / ssb + b1b);
    rwh[L] = (_Float16)oa; rwh[64 + L] = (_Float16)ob;
    __builtin_amdgcn_wave_barrier();
    float p = 0.f;
    const float4* r4 = (const float4*)(rwh + half*64); // 64 halfs = 128B = 8 b128
    #pragma unroll
    for (int q = 0; q < 8; q++){
      union { float4 f; half2v h[4]; } u;
      u.f = r4[q];                                     // same-addr broadcast b128
      #pragma unroll
      for (int j = 0; j < 4; j++)
        p = __builtin_amdgcn_fdot2(u.h[j], w2h[q*4 + j], p, false);
    }
    __builtin_amdgcn_wave_barrier();                   // reads before next iter's writes
    p += __shfl_xor(p, 32, 64);
    if (half == 0){
      h2h[(size_t)node*32 + c] = __float2half(p);      // 64B contiguous per wave
      float ps = p * asc, pd = p * adc;
      #pragma unroll
      for (int m = 16; m >= 1; m >>= 1){
        ps += __shfl_xor(ps, m, 32);
        pd += __shfl_xor(pd, m, 32);
      }
      if (c == 0){ als_s[g] = ps; ald_s[g] = pd; }     // stage in LDS
    }
  }
  __syncthreads();
  if (tid < 32){
    int node = blockIdx.x * 32 + tid;
    if (node < N){ als2[node] = als_s[tid]; ald2[node] = ald_s[tid]; }
  }
}

// ---- Layer 2 gather + fused mean-pool partials + fused MLP head (last block) ----
// block 256 = 8 nodes x 32 ch
__global__ void __launch_bounds__(256)
k_gat2(const int* __restrict__ degp, const int* __restrict__ csr_src,
       const __half* __restrict__ h2h, const float* __restrict__ als2,
       const float* __restrict__ ald2, const float* __restrict__ b2,
       const int* __restrict__ batch, float* __restrict__ gsum_part,
       const float* __restrict__ gcnt, const float* __restrict__ Wc1,
       const float* __restrict__ bc1, const float* __restrict__ Wc2,
       const float* __restrict__ bc2, float* __restrict__ out,
       int* __restrict__ done, int nblk, int N){
  int tid = threadIdx.x;
  int node = blockIdx.x * 8 + (tid >> 5);
  int c = tid & 31;
  if (node < N){
    int deg = degp[node];
    size_t r0 = (size_t)node * PAD;
    int total = deg + 1;
    float ald = ald2[node];

    float ssum = 0.f, f0 = 0.f, f1 = 0.f, f2 = 0.f, f3 = 0.f;
    for (int base = 0; base < total; base += 32){
      int t = base + c;
      int s = (t < deg) ? csr_src[r0 + t] : node;
      float ex = (t < total) ? __expf(lrelu(als2[s] + ald)) : 0.f;
      ssum += ex;
      int lim = min(32, total - base);
      int jj = 0;
      for (; jj + 4 <= lim; jj += 4){                  // 4 gathers in flight
        float e0 = __shfl(ex, jj, 32);   int s0 = __shfl(s, jj, 32);
        float e1 = __shfl(ex, jj+1, 32); int s1 = __shfl(s, jj+1, 32);
        float e2 = __shfl(ex, jj+2, 32); int s2 = __shfl(s, jj+2, 32);
        float e3 = __shfl(ex, jj+3, 32); int s3 = __shfl(s, jj+3, 32);
        float v0 = __half2float(h2h[(size_t)s0*32 + c]);
        float v1 = __half2float(h2h[(size_t)s1*32 + c]);
        float v2 = __half2float(h2h[(size_t)s2*32 + c]);
        float v3 = __half2float(h2h[(size_t)s3*32 + c]);
        f0 += e0*v0; f1 += e1*v1; f2 += e2*v2; f3 += e3*v3;
      }
      for (; jj < lim; jj++){
        float ej = __shfl(ex, jj, 32);
        int   sj = __shfl(s, jj, 32);
        f0 += ej * __half2float(h2h[(size_t)sj*32 + c]);
      }
    }
    float facc = (f0 + f1) + (f2 + f3);
    #pragma unroll
    for (int m = 16; m >= 1; m >>= 1) ssum += __shfl_xor(ssum, m, 32);
    float v = elu1(facc / ssum + b2[c]);
    int b = batch[node];
    atomicAdd(gsum_part + ((blockIdx.x & (NPART-1)) << 12) + b*32 + c, v);
  }

  // ---- last-block-done: run the MLP head once all pool partials are in ----
  __shared__ int lastblk;
  __threadfence();                                     // release gsum_part writes
  __syncthreads();
  if (tid == 0) lastblk = (atomicAdd(done, 1) == nblk - 1) ? 1 : 0;
  __syncthreads();
  if (!lastblk) return;
  __threadfence();                                     // acquire: no stale caches

  int sub = tid >> 5;                                  // 8 graphs per pass
  for (int pass = 0; pass < 16; pass++){
    int gph = pass * 8 + sub;
    float s = 0.f;
    #pragma unroll
    for (int p = 0; p < NPART; p++) s += gsum_part[(p << 12) + gph*32 + c];
    float cnt = gcnt[gph];
    cnt = cnt > 1.f ? cnt : 1.f;
    float gl = s / cnt;
    float z = bc1[c];
    #pragma unroll 8
    for (int c2 = 0; c2 < 32; c2++) z += __shfl(gl, c2, 32) * Wc1[c2*32 + c];
    z = z > 0.f ? z : 0.f;
    float r = z * Wc2[c];
    #pragma unroll
    for (int m = 16; m >= 1; m >>= 1) r += __shfl_xor(r, m, 32);
    if (c == 0) out[gph] = 1.f / (1.f + expf(-(r + bc2[0])));
  }
}

extern "C" void kernel_launch(void* const* d_in, const int* in_sizes, int n_in,
                              void* d_out, int out_size, void* d_ws, size_t ws_size,
                              hipStream_t stream){
  const float* x   = (const float*)d_in[0];
  const int*   ei  = (const int*)d_in[1];
  const int*   bat = (const int*)d_in[2];
  const float* W1  = (const float*)d_in[3];
  const float* as1 = (const float*)d_in[4];
  const float* ad1 = (const float*)d_in[5];
  const float* b1  = (const float*)d_in[6];
  const float* W2  = (const float*)d_in[7];
  const float* as2 = (const float*)d_in[8];
  const float* ad2 = (const float*)d_in[9];
  const float* b2  = (const float*)d_in[10];
  const float* Wc1 = (const float*)d_in[11];
  const float* bc1 = (const float*)d_in[12];
  const float* Wc2 = (const float*)d_in[13];
  const float* bc2 = (const float*)d_in[14];
  float* out = (float*)d_out;

  const int N = in_sizes[2];
  const int E = in_sizes[1] / 2;

  float* ws = (float*)d_ws;
  size_t off = 0;
  // zero-init region (single memset): cur + gsum_part + gcnt + done
  int* cur    = (int*)ws;           off += (size_t)N;        // becomes deg after k_scat
  float* gsum_part = ws + off;      off += (size_t)NPART * 4096;
  float* gcnt = ws + off;           off += 128;
  int* done   = (int*)(ws + off);   off += 4;
  const size_t zero_elems = off;
  __half* h2h = (__half*)(ws + off); off += (size_t)N * 16;  // N*32 halfs
  float* als2 = ws + off;           off += (size_t)N;
  float* ald2 = ws + off;           off += (size_t)N;
  int* csr_src= (int*)(ws + off);   off += (size_t)N * PAD;  // 128B-aligned rows

  hipMemsetAsync(d_ws, 0, zero_elems * sizeof(float), stream);

  // padded-CSR build + gcnt histogram (fused, single edge pass)
  k_scat<<<(E + 255) / 256, 256, 0, stream>>>(ei, bat, cur, csr_src, gcnt, N, E);

  // fused layer 1 (+ h2 f16 + layer-2 logits)
  k_layer1<<<(N + 31) / 32, 256, 0, stream>>>(cur, csr_src, x, W1, as1, ad1, b1,
                                              W2, as2, ad2, h2h, als2, ald2, N);

  // layer 2 gather + pool partials + fused head (last block)
  int nblk = (N + 7) / 8;
  k_gat2<<<nblk, 256, 0, stream>>>(cur, csr_src, h2h, als2, ald2, b2, bat,
                                   gsum_part, gcnt, Wc1, bc1, Wc2, bc2, out,
                                   done, nblk, N);
}

// Round 18
// 193.297 us; speedup vs baseline: 5.5902x; 5.5902x over previous
//
#include <hip/hip_runtime.h>
#include <hip/hip_fp16.h>
#include <float.h>

#define NEG 0.2f
#define NPART 16
#define PAD 32   // row stride = 128B (one line); deg ~ Poisson(6), P(>=32) ~ 1e-15

typedef _Float16 half2v __attribute__((ext_vector_type(2)));

__device__ __forceinline__ float lrelu(float x){ return x > 0.f ? x : NEG * x; }
__device__ __forceinline__ float elu1(float x){ return x > 0.f ? x : (__expf(x) - 1.f); }

// ---- Padded-CSR build + per-graph node counts (fused) ----
// cur[] pre-zeroed; after this pass cur[node] == in-degree
__global__ void k_scat(const int* __restrict__ ei, const int* __restrict__ batch,
                       int* __restrict__ cur, int* __restrict__ csr_src,
                       float* __restrict__ gcnt, int N, int E){
  __shared__ float gc[128];
  int tid = threadIdx.x;
  bool doh = blockIdx.x < 256;                         // block-uniform
  if (doh && tid < 128) gc[tid] = 0.f;
  __syncthreads();
  int idx = blockIdx.x * 256 + tid;
  int gstr = gridDim.x * 256;
  for (int e = idx; e < E; e += gstr){
    int s = ei[e], d = ei[E + e];
    int pos = atomicAdd(cur + d, 1);
    if (pos < PAD) csr_src[(size_t)d * PAD + pos] = s; // guard impossible overflow
  }
  if (doh){
    for (int n = idx; n < N; n += 256 * 256)
      atomicAdd(&gc[batch[n]], 1.f);
    __syncthreads();
    if (tid < 128 && gc[tid] != 0.f) atomicAdd(gcnt + tid, gc[tid]);
  }
}

// ---- Fused layer 1: edge accumulation (linearity trick) + out1 + h2 + L2 logits
// phase 1: 8 lanes/node; first-round loads (deg, csr word, x rows) hoisted above
//          the PQ preamble -> dependent-chain depth 3->2, overlapped with barrier.
// phase 2: out1 f16 in LDS; GEMV via v_dot2_f32_f16 (W2 in 32 packed half2 regs)
// NOTE: min-waves 6 (not 8): 8 forces a 64-VGPR budget -> scratch spill (R15).
__global__ void __launch_bounds__(256, 6)
k_layer1(const int* __restrict__ degp, const int* __restrict__ csr_src,
         const float* __restrict__ x, const float* __restrict__ W1,
         const float* __restrict__ as1, const float* __restrict__ ad1,
         const float* __restrict__ b1, const float* __restrict__ W2,
         const float* __restrict__ as2, const float* __restrict__ ad2,
         __half* __restrict__ h2h, float* __restrict__ als2,
         float* __restrict__ ald2, int N){
  __shared__ float PQ[2][16];                          // [which][k*4+h]
  __shared__ __align__(16) float xa[32][20];           // per-node {acc[16], ss[4]}
  __shared__ __align__(16) _Float16 rowsh[4][128];     // per-wave out1 (f16)
  __shared__ float als_s[32], ald_s[32];               // staged L2-logit outputs
  int tid = threadIdx.x;
  const float4* x4 = (const float4*)x;

  // ---- speculative first-round loads (before PQ compute + barrier) ----
  int g1 = tid >> 3, l = tid & 7;
  int node1 = blockIdx.x * 32 + g1;
  int nd = node1 < N ? node1 : N - 1;
  int deg = degp[nd];                                  // load A
  size_t r0 = (size_t)nd * PAD;
  int s_pre = csr_src[r0 + l];                         // load B (indep of A)
  int total = (node1 < N) ? deg + 1 : 0;
  int s0 = (l < deg) ? s_pre : nd;                     // sanitize poison beyond deg
  float4 xv0 = x4[s0];                                 // gather (depth 2)
  float4 xn = x4[nd];

  if (tid < 32){
    int which = tid >> 4, kh = tid & 15, k = kh >> 2, h = kh & 3;
    const float* a = which ? ad1 : as1;
    float s = 0.f;
    #pragma unroll 8
    for (int c = 0; c < 32; c++) s += W1[k*128 + h*32 + c] * a[h*32 + c];
    PQ[which][kh] = s;
  }
  __syncthreads();

  // ---- phase 1: 8 lanes per node ----
  {
    float P[16], Q[16];
    #pragma unroll
    for (int i = 0; i < 16; i++){ P[i] = PQ[0][i]; Q[i] = PQ[1][i]; }
    float ald0 = xn.x*Q[0] + xn.y*Q[4] + xn.z*Q[8]  + xn.w*Q[12];
    float ald1_ = xn.x*Q[1] + xn.y*Q[5] + xn.z*Q[9]  + xn.w*Q[13];
    float ald2_ = xn.x*Q[2] + xn.y*Q[6] + xn.z*Q[10] + xn.w*Q[14];
    float ald3 = xn.x*Q[3] + xn.y*Q[7] + xn.z*Q[11] + xn.w*Q[15];
    float acc[16];
    #pragma unroll
    for (int i = 0; i < 16; i++) acc[i] = 0.f;
    float ss[4] = {0.f, 0.f, 0.f, 0.f};
    if (l < total){                                    // first round: preloaded
      float4 xv = xv0;
      float a0 = xv.x*P[0] + xv.y*P[4] + xv.z*P[8]  + xv.w*P[12];
      float a1 = xv.x*P[1] + xv.y*P[5] + xv.z*P[9]  + xv.w*P[13];
      float a2 = xv.x*P[2] + xv.y*P[6] + xv.z*P[10] + xv.w*P[14];
      float a3 = xv.x*P[3] + xv.y*P[7] + xv.z*P[11] + xv.w*P[15];
      float e0 = __expf(lrelu(a0 + ald0));
      float e1 = __expf(lrelu(a1 + ald1_));
      float e2 = __expf(lrelu(a2 + ald2_));
      float e3 = __expf(lrelu(a3 + ald3));
      ss[0] += e0; ss[1] += e1; ss[2] += e2; ss[3] += e3;
      acc[0]  += e0*xv.x; acc[1]  += e0*xv.y; acc[2]  += e0*xv.z; acc[3]  += e0*xv.w;
      acc[4]  += e1*xv.x; acc[5]  += e1*xv.y; acc[6]  += e1*xv.z; acc[7]  += e1*xv.w;
      acc[8]  += e2*xv.x; acc[9]  += e2*xv.y; acc[10] += e2*xv.z; acc[11] += e2*xv.w;
      acc[12] += e3*xv.x; acc[13] += e3*xv.y; acc[14] += e3*xv.z; acc[15] += e3*xv.w;
    }
    for (int t = l + 8; t < total; t += 8){            // rare (P(deg>=8) ~ 0.26)
      int s = (t < deg) ? csr_src[r0 + t] : nd;
      float4 xv = x4[s];
      float a0 = xv.x*P[0] + xv.y*P[4] + xv.z*P[8]  + xv.w*P[12];
      float a1 = xv.x*P[1] + xv.y*P[5] + xv.z*P[9]  + xv.w*P[13];
      float a2 = xv.x*P[2] + xv.y*P[6] + xv.z*P[10] + xv.w*P[14];
      float a3 = xv.x*P[3] + xv.y*P[7] + xv.z*P[11] + xv.w*P[15];
      float e0 = __expf(lrelu(a0 + ald0));
      float e1 = __expf(lrelu(a1 + ald1_));
      float e2 = __expf(lrelu(a2 + ald2_));
      float e3 = __expf(lrelu(a3 + ald3));
      ss[0] += e0; ss[1] += e1; ss[2] += e2; ss[3] += e3;
      acc[0]  += e0*xv.x; acc[1]  += e0*xv.y; acc[2]  += e0*xv.z; acc[3]  += e0*xv.w;
      acc[4]  += e1*xv.x; acc[5]  += e1*xv.y; acc[6]  += e1*xv.z; acc[7]  += e1*xv.w;
      acc[8]  += e2*xv.x; acc[9]  += e2*xv.y; acc[10] += e2*xv.z; acc[11] += e2*xv.w;
      acc[12] += e3*xv.x; acc[13] += e3*xv.y; acc[14] += e3*xv.z; acc[15] += e3*xv.w;
    }
    #pragma unroll
    for (int m = 4; m >= 1; m >>= 1){
      #pragma unroll
      for (int i = 0; i < 16; i++) acc[i] += __shfl_xor(acc[i], m, 8);
      #pragma unroll
      for (int i = 0; i < 4; i++)  ss[i]  += __shfl_xor(ss[i], m, 8);
    }
    if (l == 0){
      float* o = xa[g1];
      *(float4*)(o)      = make_float4(acc[0],  acc[1],  acc[2],  acc[3]);
      *(float4*)(o + 4)  = make_float4(acc[4],  acc[5],  acc[6],  acc[7]);
      *(float4*)(o + 8)  = make_float4(acc[8],  acc[9],  acc[10], acc[11]);
      *(float4*)(o + 12) = make_float4(acc[12], acc[13], acc[14], acc[15]);
      *(float4*)(o + 16) = make_float4(ss[0], ss[1], ss[2], ss[3]);
    }
  }
  __syncthreads();
  __builtin_amdgcn_sched_barrier(0);   // keep phase-2 weight loads below phase 1

  // ---- phase-2 constants: live range starts after phase 1 (no spill) ----
  int L = tid & 63, w = tid >> 6;
  int half = L >> 5, c = L & 31;
  half2v w2h[32];
  #pragma unroll
  for (int kk = 0; kk < 32; kk++){
    half2v t;
    t.x = (_Float16)W2[(half*64 + 2*kk)*32 + c];
    t.y = (_Float16)W2[(half*64 + 2*kk + 1)*32 + c];
    w2h[kk] = t;
  }
  float w1a[4], w1b[4];
  #pragma unroll
  for (int k = 0; k < 4; k++){ w1a[k] = W1[k*128 + L]; w1b[k] = W1[k*128 + 64 + L]; }
  float b1a = b1[L], b1b = b1[64 + L];
  float asc = as2[c], adc = ad2[c];
  int ha = L >> 5, hb = 2 + (L >> 5);
  _Float16* rwh = rowsh[w];

  // ---- phase 2: each wave handles 8 nodes; GEMV via fdot2 ----
  for (int i = 0; i < 8; i++){
    int g = w*8 + i;
    int node = blockIdx.x * 32 + g;
    if (node >= N) continue;                           // wave-uniform
    const float* xg = xa[g];
    float4 xva = *(const float4*)(xg + ha*4);          // broadcast LDS
    float4 xvb = *(const float4*)(xg + hb*4);
    float ssa = xg[16 + ha], ssb = xg[16 + hb];
    float oa = elu1((xva.x*w1a[0] + xva.y*w1a[1] + xva.z*w1a[2] + xva.w*w1a[3]) / ssa + b1a);
    float ob = elu1((xvb.x*w1b[0] + xvb.y*w1b[1] + xvb.z*w1b[2] + xvb.w*w1b[3]) / ssb + b1b);
    rwh[L] = (_Float16)oa; rwh[64 + L] = (_Float16)ob;
    __builtin_amdgcn_wave_barrier();
    float p = 0.f;
    const float4* r4 = (const float4*)(rwh + half*64); // 64 halfs = 128B = 8 b128
    #pragma unroll
    for (int q = 0; q < 8; q++){
      union { float4 f; half2v h[4]; } u;
      u.f = r4[q];                                     // same-addr broadcast b128
      #pragma unroll
      for (int j = 0; j < 4; j++)
        p = __builtin_amdgcn_fdot2(u.h[j], w2h[q*4 + j], p, false);
    }
    __builtin_amdgcn_wave_barrier();                   // reads before next iter's writes
    p += __shfl_xor(p, 32, 64);
    if (half == 0){
      h2h[(size_t)node*32 + c] = __float2half(p);      // 64B contiguous per wave
      float ps = p * asc, pd = p * adc;
      #pragma unroll
      for (int m = 16; m >= 1; m >>= 1){
        ps += __shfl_xor(ps, m, 32);
        pd += __shfl_xor(pd, m, 32);
      }
      if (c == 0){ als_s[g] = ps; ald_s[g] = pd; }     // stage in LDS
    }
  }
  __syncthreads();
  if (tid < 32){
    int node = blockIdx.x * 32 + tid;
    if (node < N){ als2[node] = als_s[tid]; ald2[node] = ald_s[tid]; }
  }
}

// ---- Layer 2 gather (f16 h2, unrolled x4) + fused mean-pool partials ----
// block 256 = 8 nodes x 32 ch.  NO device fences here: R17's per-block
// __threadfence (last-block-done head fusion) cost 935us @ 1.4% VALUBusy.
__global__ void __launch_bounds__(256)
k_gat2(const int* __restrict__ degp, const int* __restrict__ csr_src,
       const __half* __restrict__ h2h, const float* __restrict__ als2,
       const float* __restrict__ ald2, const float* __restrict__ b2,
       const int* __restrict__ batch, float* __restrict__ gsum_part, int N){
  int tid = threadIdx.x;
  int node = blockIdx.x * 8 + (tid >> 5);
  if (node >= N) return;
  int c = tid & 31;
  int deg = degp[node];
  size_t r0 = (size_t)node * PAD;
  int total = deg + 1;
  float ald = ald2[node];

  float ssum = 0.f, f0 = 0.f, f1 = 0.f, f2 = 0.f, f3 = 0.f;
  for (int base = 0; base < total; base += 32){
    int t = base + c;
    int s = (t < deg) ? csr_src[r0 + t] : node;
    float ex = (t < total) ? __expf(lrelu(als2[s] + ald)) : 0.f;
    ssum += ex;
    int lim = min(32, total - base);
    int jj = 0;
    for (; jj + 4 <= lim; jj += 4){                    // 4 gathers in flight
      float e0 = __shfl(ex, jj, 32);   int s0 = __shfl(s, jj, 32);
      float e1 = __shfl(ex, jj+1, 32); int s1 = __shfl(s, jj+1, 32);
      float e2 = __shfl(ex, jj+2, 32); int s2 = __shfl(s, jj+2, 32);
      float e3 = __shfl(ex, jj+3, 32); int s3 = __shfl(s, jj+3, 32);
      float v0 = __half2float(h2h[(size_t)s0*32 + c]);
      float v1 = __half2float(h2h[(size_t)s1*32 + c]);
      float v2 = __half2float(h2h[(size_t)s2*32 + c]);
      float v3 = __half2float(h2h[(size_t)s3*32 + c]);
      f0 += e0*v0; f1 += e1*v1; f2 += e2*v2; f3 += e3*v3;
    }
    for (; jj < lim; jj++){
      float ej = __shfl(ex, jj, 32);
      int   sj = __shfl(s, jj, 32);
      f0 += ej * __half2float(h2h[(size_t)sj*32 + c]);
    }
  }
  float facc = (f0 + f1) + (f2 + f3);
  #pragma unroll
  for (int m = 16; m >= 1; m >>= 1) ssum += __shfl_xor(ssum, m, 32);
  float v = elu1(facc / ssum + b2[c]);
  int b = batch[node];
  atomicAdd(gsum_part + ((blockIdx.x & (NPART-1)) << 12) + b*32 + c, v);
}

// ---- MLP head: reduce partials + divide + 2-layer MLP ----
__global__ void k_head(const float* __restrict__ gsum_part, const float* __restrict__ gcnt,
                       const float* __restrict__ Wc1, const float* __restrict__ bc1,
                       const float* __restrict__ Wc2, const float* __restrict__ bc2,
                       float* __restrict__ out){
  int g = blockIdx.x, tid = threadIdx.x;
  __shared__ float gl[32];
  if (tid < 32){
    float s = 0.f;
    #pragma unroll
    for (int p = 0; p < NPART; p++) s += gsum_part[(p << 12) + g*32 + tid];
    float cnt = gcnt[g];
    cnt = cnt > 1.f ? cnt : 1.f;
    gl[tid] = s / cnt;
  }
  __syncthreads();
  if (tid < 32){
    float z = bc1[tid];
    #pragma unroll 8
    for (int c2 = 0; c2 < 32; c2++) z += gl[c2] * Wc1[c2*32 + tid];
    z = z > 0.f ? z : 0.f;
    float r = z * Wc2[tid];
    #pragma unroll
    for (int m = 16; m >= 1; m >>= 1) r += __shfl_xor(r, m, 32);
    if (tid == 0) out[g] = 1.f / (1.f + expf(-(r + bc2[0])));
  }
}

extern "C" void kernel_launch(void* const* d_in, const int* in_sizes, int n_in,
                              void* d_out, int out_size, void* d_ws, size_t ws_size,
                              hipStream_t stream){
  const float* x   = (const float*)d_in[0];
  const int*   ei  = (const int*)d_in[1];
  const int*   bat = (const int*)d_in[2];
  const float* W1  = (const float*)d_in[3];
  const float* as1 = (const float*)d_in[4];
  const float* ad1 = (const float*)d_in[5];
  const float* b1  = (const float*)d_in[6];
  const float* W2  = (const float*)d_in[7];
  const float* as2 = (const float*)d_in[8];
  const float* ad2 = (const float*)d_in[9];
  const float* b2  = (const float*)d_in[10];
  const float* Wc1 = (const float*)d_in[11];
  const float* bc1 = (const float*)d_in[12];
  const float* Wc2 = (const float*)d_in[13];
  const float* bc2 = (const float*)d_in[14];
  float* out = (float*)d_out;

  const int N = in_sizes[2];
  const int E = in_sizes[1] / 2;

  float* ws = (float*)d_ws;
  size_t off = 0;
  // zero-init region (single memset): cur + gsum_part + gcnt
  int* cur    = (int*)ws;           off += (size_t)N;        // becomes deg after k_scat
  float* gsum_part = ws + off;      off += (size_t)NPART * 4096;
  float* gcnt = ws + off;           off += 128;
  const size_t zero_elems = off;
  __half* h2h = (__half*)(ws + off); off += (size_t)N * 16;  // N*32 halfs
  float* als2 = ws + off;           off += (size_t)N;
  float* ald2 = ws + off;           off += (size_t)N;
  int* csr_src= (int*)(ws + off);   off += (size_t)N * PAD;  // 128B-aligned rows

  hipMemsetAsync(d_ws, 0, zero_elems * sizeof(float), stream);

  // padded-CSR build + gcnt histogram (fused, single edge pass)
  k_scat<<<(E + 255) / 256, 256, 0, stream>>>(ei, bat, cur, csr_src, gcnt, N, E);

  // fused layer 1 (+ h2 f16 + layer-2 logits)
  k_layer1<<<(N + 31) / 32, 256, 0, stream>>>(cur, csr_src, x, W1, as1, ad1, b1,
                                              W2, as2, ad2, h2h, als2, ald2, N);

  // layer 2 gather + fused pool partials
  k_gat2<<<(N + 7) / 8, 256, 0, stream>>>(cur, csr_src, h2h, als2, ald2, b2,
                                          bat, gsum_part, N);

  // head (reduces partials)
  k_head<<<128, 64, 0, stream>>>(gsum_part, gcnt, Wc1, bc1, Wc2, bc2, out);
}

// Round 19
// 191.577 us; speedup vs baseline: 5.6403x; 1.0090x over previous
//
#include <hip/hip_runtime.h>
#include <hip/hip_fp16.h>
#include <float.h>

#define NEG 0.2f
#define NPART 16
#define PAD 32   // row stride = 128B (one line); deg ~ Poisson(6), P(>=32) ~ 1e-15

typedef _Float16 half2v __attribute__((ext_vector_type(2)));

__device__ __forceinline__ float lrelu(float x){ return x > 0.f ? x : NEG * x; }
__device__ __forceinline__ float elu1(float x){ return x > 0.f ? x : (__expf(x) - 1.f); }

// ---- Padded-CSR build + per-graph node counts (fused) ----
// cur[] pre-zeroed; after this pass cur[node] == in-degree
__global__ void k_scat(const int* __restrict__ ei, const int* __restrict__ batch,
                       int* __restrict__ cur, int* __restrict__ csr_src,
                       float* __restrict__ gcnt, int N, int E){
  __shared__ float gc[128];
  int tid = threadIdx.x;
  bool doh = blockIdx.x < 256;                         // block-uniform
  if (doh && tid < 128) gc[tid] = 0.f;
  __syncthreads();
  int idx = blockIdx.x * 256 + tid;
  int gstr = gridDim.x * 256;
  for (int e = idx; e < E; e += gstr){
    int s = ei[e], d = ei[E + e];
    int pos = atomicAdd(cur + d, 1);
    if (pos < PAD) csr_src[(size_t)d * PAD + pos] = s; // guard impossible overflow
  }
  if (doh){
    for (int n = idx; n < N; n += 256 * 256)
      atomicAdd(&gc[batch[n]], 1.f);
    __syncthreads();
    if (tid < 128 && gc[tid] != 0.f) atomicAdd(gcnt + tid, gc[tid]);
  }
}

// ---- Fused layer 1: edge accumulation (linearity trick) + out1 + h2 + L2 logits
// phase 1: 8 lanes/node; first-round loads hoisted above the PQ preamble.
// phase 2: out1 f16 in LDS; GEMV via v_dot2_f32_f16 (W2 in 32 packed half2 regs)
// NOTE: min-waves 6 (not 8): 8 forces a 64-VGPR budget -> scratch spill (R15).
__global__ void __launch_bounds__(256, 6)
k_layer1(const int* __restrict__ degp, const int* __restrict__ csr_src,
         const float* __restrict__ x, const float* __restrict__ W1,
         const float* __restrict__ as1, const float* __restrict__ ad1,
         const float* __restrict__ b1, const float* __restrict__ W2,
         const float* __restrict__ as2, const float* __restrict__ ad2,
         __half* __restrict__ h2h, float* __restrict__ als2,
         float* __restrict__ ald2, int N){
  __shared__ float PQ[2][16];                          // [which][k*4+h]
  __shared__ __align__(16) float xa[32][20];           // per-node {acc[16], ss[4]}
  __shared__ __align__(16) _Float16 rowsh[4][128];     // per-wave out1 (f16)
  __shared__ float als_s[32], ald_s[32];               // staged L2-logit outputs
  int tid = threadIdx.x;
  const float4* x4 = (const float4*)x;

  // ---- speculative first-round loads (before PQ compute + barrier) ----
  int g1 = tid >> 3, l = tid & 7;
  int node1 = blockIdx.x * 32 + g1;
  int nd = node1 < N ? node1 : N - 1;
  int deg = degp[nd];                                  // load A
  size_t r0 = (size_t)nd * PAD;
  int s_pre = csr_src[r0 + l];                         // load B (indep of A)
  int total = (node1 < N) ? deg + 1 : 0;
  int s0 = (l < deg) ? s_pre : nd;                     // sanitize poison beyond deg
  float4 xv0 = x4[s0];                                 // gather (depth 2)
  float4 xn = x4[nd];

  if (tid < 32){
    int which = tid >> 4, kh = tid & 15, k = kh >> 2, h = kh & 3;
    const float* a = which ? ad1 : as1;
    float s = 0.f;
    #pragma unroll 8
    for (int c = 0; c < 32; c++) s += W1[k*128 + h*32 + c] * a[h*32 + c];
    PQ[which][kh] = s;
  }
  __syncthreads();

  // ---- phase 1: 8 lanes per node ----
  {
    float P[16], Q[16];
    #pragma unroll
    for (int i = 0; i < 16; i++){ P[i] = PQ[0][i]; Q[i] = PQ[1][i]; }
    float ald0 = xn.x*Q[0] + xn.y*Q[4] + xn.z*Q[8]  + xn.w*Q[12];
    float ald1_ = xn.x*Q[1] + xn.y*Q[5] + xn.z*Q[9]  + xn.w*Q[13];
    float ald2_ = xn.x*Q[2] + xn.y*Q[6] + xn.z*Q[10] + xn.w*Q[14];
    float ald3 = xn.x*Q[3] + xn.y*Q[7] + xn.z*Q[11] + xn.w*Q[15];
    float acc[16];
    #pragma unroll
    for (int i = 0; i < 16; i++) acc[i] = 0.f;
    float ss[4] = {0.f, 0.f, 0.f, 0.f};
    if (l < total){                                    // first round: preloaded
      float4 xv = xv0;
      float a0 = xv.x*P[0] + xv.y*P[4] + xv.z*P[8]  + xv.w*P[12];
      float a1 = xv.x*P[1] + xv.y*P[5] + xv.z*P[9]  + xv.w*P[13];
      float a2 = xv.x*P[2] + xv.y*P[6] + xv.z*P[10] + xv.w*P[14];
      float a3 = xv.x*P[3] + xv.y*P[7] + xv.z*P[11] + xv.w*P[15];
      float e0 = __expf(lrelu(a0 + ald0));
      float e1 = __expf(lrelu(a1 + ald1_));
      float e2 = __expf(lrelu(a2 + ald2_));
      float e3 = __expf(lrelu(a3 + ald3));
      ss[0] += e0; ss[1] += e1; ss[2] += e2; ss[3] += e3;
      acc[0]  += e0*xv.x; acc[1]  += e0*xv.y; acc[2]  += e0*xv.z; acc[3]  += e0*xv.w;
      acc[4]  += e1*xv.x; acc[5]  += e1*xv.y; acc[6]  += e1*xv.z; acc[7]  += e1*xv.w;
      acc[8]  += e2*xv.x; acc[9]  += e2*xv.y; acc[10] += e2*xv.z; acc[11] += e2*xv.w;
      acc[12] += e3*xv.x; acc[13] += e3*xv.y; acc[14] += e3*xv.z; acc[15] += e3*xv.w;
    }
    for (int t = l + 8; t < total; t += 8){            // rare (P(deg>=8) ~ 0.26)
      int s = (t < deg) ? csr_src[r0 + t] : nd;
      float4 xv = x4[s];
      float a0 = xv.x*P[0] + xv.y*P[4] + xv.z*P[8]  + xv.w*P[12];
      float a1 = xv.x*P[1] + xv.y*P[5] + xv.z*P[9]  + xv.w*P[13];
      float a2 = xv.x*P[2] + xv.y*P[6] + xv.z*P[10] + xv.w*P[14];
      float a3 = xv.x*P[3] + xv.y*P[7] + xv.z*P[11] + xv.w*P[15];
      float e0 = __expf(lrelu(a0 + ald0));
      float e1 = __expf(lrelu(a1 + ald1_));
      float e2 = __expf(lrelu(a2 + ald2_));
      float e3 = __expf(lrelu(a3 + ald3));
      ss[0] += e0; ss[1] += e1; ss[2] += e2; ss[3] += e3;
      acc[0]  += e0*xv.x; acc[1]  += e0*xv.y; acc[2]  += e0*xv.z; acc[3]  += e0*xv.w;
      acc[4]  += e1*xv.x; acc[5]  += e1*xv.y; acc[6]  += e1*xv.z; acc[7]  += e1*xv.w;
      acc[8]  += e2*xv.x; acc[9]  += e2*xv.y; acc[10] += e2*xv.z; acc[11] += e2*xv.w;
      acc[12] += e3*xv.x; acc[13] += e3*xv.y; acc[14] += e3*xv.z; acc[15] += e3*xv.w;
    }
    #pragma unroll
    for (int m = 4; m >= 1; m >>= 1){
      #pragma unroll
      for (int i = 0; i < 16; i++) acc[i] += __shfl_xor(acc[i], m, 8);
      #pragma unroll
      for (int i = 0; i < 4; i++)  ss[i]  += __shfl_xor(ss[i], m, 8);
    }
    if (l == 0){
      float* o = xa[g1];
      *(float4*)(o)      = make_float4(acc[0],  acc[1],  acc[2],  acc[3]);
      *(float4*)(o + 4)  = make_float4(acc[4],  acc[5],  acc[6],  acc[7]);
      *(float4*)(o + 8)  = make_float4(acc[8],  acc[9],  acc[10], acc[11]);
      *(float4*)(o + 12) = make_float4(acc[12], acc[13], acc[14], acc[15]);
      *(float4*)(o + 16) = make_float4(ss[0], ss[1], ss[2], ss[3]);
    }
  }
  __syncthreads();
  __builtin_amdgcn_sched_barrier(0);   // keep phase-2 weight loads below phase 1

  // ---- phase-2 constants: live range starts after phase 1 (no spill) ----
  int L = tid & 63, w = tid >> 6;
  int half = L >> 5, c = L & 31;
  half2v w2h[32];
  #pragma unroll
  for (int kk = 0; kk < 32; kk++){
    half2v t;
    t.x = (_Float16)W2[(half*64 + 2*kk)*32 + c];
    t.y = (_Float16)W2[(half*64 + 2*kk + 1)*32 + c];
    w2h[kk] = t;
  }
  float w1a[4], w1b[4];
  #pragma unroll
  for (int k = 0; k < 4; k++){ w1a[k] = W1[k*128 + L]; w1b[k] = W1[k*128 + 64 + L]; }
  float b1a = b1[L], b1b = b1[64 + L];
  float asc = as2[c], adc = ad2[c];
  int ha = L >> 5, hb = 2 + (L >> 5);
  _Float16* rwh = rowsh[w];

  // ---- phase 2: each wave handles 8 nodes; GEMV via fdot2 ----
  for (int i = 0; i < 8; i++){
    int g = w*8 + i;
    int node = blockIdx.x * 32 + g;
    if (node >= N) continue;                           // wave-uniform
    const float* xg = xa[g];
    float4 xva = *(const float4*)(xg + ha*4);          // broadcast LDS
    float4 xvb = *(const float4*)(xg + hb*4);
    float ssa = xg[16 + ha], ssb = xg[16 + hb];
    float oa = elu1((xva.x*w1a[0] + xva.y*w1a[1] + xva.z*w1a[2] + xva.w*w1a[3]) / ssa + b1a);
    float ob = elu1((xvb.x*w1b[0] + xvb.y*w1b[1] + xvb.z*w1b[2] + xvb.w*w1b[3]) / ssb + b1b);
    rwh[L] = (_Float16)oa; rwh[64 + L] = (_Float16)ob;
    __builtin_amdgcn_wave_barrier();
    float p = 0.f;
    const float4* r4 = (const float4*)(rwh + half*64); // 64 halfs = 128B = 8 b128
    #pragma unroll
    for (int q = 0; q < 8; q++){
      union { float4 f; half2v h[4]; } u;
      u.f = r4[q];                                     // same-addr broadcast b128
      #pragma unroll
      for (int j = 0; j < 4; j++)
        p = __builtin_amdgcn_fdot2(u.h[j], w2h[q*4 + j], p, false);
    }
    __builtin_amdgcn_wave_barrier();                   // reads before next iter's writes
    p += __shfl_xor(p, 32, 64);
    if (half == 0){
      h2h[(size_t)node*32 + c] = __float2half(p);      // 64B contiguous per wave
      float ps = p * asc, pd = p * adc;
      #pragma unroll
      for (int m = 16; m >= 1; m >>= 1){
        ps += __shfl_xor(ps, m, 32);
        pd += __shfl_xor(pd, m, 32);
      }
      if (c == 0){ als_s[g] = ps; ald_s[g] = pd; }     // stage in LDS
    }
  }
  __syncthreads();
  if (tid < 32){
    int node = blockIdx.x * 32 + tid;
    if (node < N){ als2[node] = als_s[tid]; ald2[node] = ald_s[tid]; }
  }
}

// ---- Layer 2 gather (half2: 2 ch/lane, 2 edges per iteration) + pool partials ----
// block 256 = 8 nodes x 32 lanes; lanes 0-15 -> edge jj, 16-31 -> edge jj+1.
// NO device fences here (R17 lesson: per-block __threadfence = 935us).
__global__ void __launch_bounds__(256)
k_gat2(const int* __restrict__ degp, const int* __restrict__ csr_src,
       const __half* __restrict__ h2h, const float* __restrict__ als2,
       const float* __restrict__ ald2, const float* __restrict__ b2,
       const int* __restrict__ batch, float* __restrict__ gsum_part, int N){
  int tid = threadIdx.x;
  int node = blockIdx.x * 8 + (tid >> 5);
  if (node >= N) return;
  int lane = tid & 31;
  int c2 = lane & 15;                                  // channel pair: 2c2, 2c2+1
  int sub = lane >> 4;                                 // which edge of the pair
  int deg = degp[node];
  size_t r0 = (size_t)node * PAD;
  int total = deg + 1;
  float ald = ald2[node];

  float ssum = 0.f;
  float fx0 = 0.f, fy0 = 0.f, fx1 = 0.f, fy1 = 0.f;
  for (int base = 0; base < total; base += 32){
    int t = base + lane;
    int s = (t < deg) ? csr_src[r0 + t] : node;
    float ex = (t < total) ? __expf(lrelu(als2[s] + ald)) : 0.f;
    ssum += ex;
    int lim = min(32, total - base);
    int jj = 0;
    for (; jj + 4 <= lim; jj += 4){                    // 2 pairs in flight
      int ja = jj + sub, jb = jj + 2 + sub;
      float ea = __shfl(ex, ja, 32); int sa = __shfl(s, ja, 32);
      float eb = __shfl(ex, jb, 32); int sb = __shfl(s, jb, 32);
      float2 va = __half22float2(*(const __half2*)(h2h + (size_t)sa*32 + 2*c2));
      float2 vb = __half22float2(*(const __half2*)(h2h + (size_t)sb*32 + 2*c2));
      fx0 += ea*va.x; fy0 += ea*va.y;
      fx1 += eb*vb.x; fy1 += eb*vb.y;
    }
    for (; jj < lim; jj += 2){                         // tail (guarded pair)
      int j2 = jj + sub;
      float ej = (j2 < lim) ? __shfl(ex, j2, 32) : 0.f;
      int   sj = __shfl(s, (j2 < lim) ? j2 : jj, 32);
      float2 v = __half22float2(*(const __half2*)(h2h + (size_t)sj*32 + 2*c2));
      fx0 += ej*v.x; fy0 += ej*v.y;
    }
  }
  float fx = fx0 + fx1, fy = fy0 + fy1;
  fx += __shfl_xor(fx, 16, 32);                        // combine sub halves
  fy += __shfl_xor(fy, 16, 32);
  #pragma unroll
  for (int m = 16; m >= 1; m >>= 1) ssum += __shfl_xor(ssum, m, 32);
  // lane -> channel 2*c2+sub: each of 32 lanes writes exactly one channel
  float fc = sub ? fy : fx;
  int ch = 2*c2 + sub;
  float v = elu1(fc / ssum + b2[ch]);
  int b = batch[node];
  atomicAdd(gsum_part + ((blockIdx.x & (NPART-1)) << 12) + b*32 + ch, v);
}

// ---- MLP head: reduce partials + divide + 2-layer MLP ----
__global__ void k_head(const float* __restrict__ gsum_part, const float* __restrict__ gcnt,
                       const float* __restrict__ Wc1, const float* __restrict__ bc1,
                       const float* __restrict__ Wc2, const float* __restrict__ bc2,
                       float* __restrict__ out){
  int g = blockIdx.x, tid = threadIdx.x;
  __shared__ float gl[32];
  if (tid < 32){
    float s = 0.f;
    #pragma unroll
    for (int p = 0; p < NPART; p++) s += gsum_part[(p << 12) + g*32 + tid];
    float cnt = gcnt[g];
    cnt = cnt > 1.f ? cnt : 1.f;
    gl[tid] = s / cnt;
  }
  __syncthreads();
  if (tid < 32){
    float z = bc1[tid];
    #pragma unroll 8
    for (int c2 = 0; c2 < 32; c2++) z += gl[c2] * Wc1[c2*32 + tid];
    z = z > 0.f ? z : 0.f;
    float r = z * Wc2[tid];
    #pragma unroll
    for (int m = 16; m >= 1; m >>= 1) r += __shfl_xor(r, m, 32);
    if (tid == 0) out[g] = 1.f / (1.f + expf(-(r + bc2[0])));
  }
}

extern "C" void kernel_launch(void* const* d_in, const int* in_sizes, int n_in,
                              void* d_out, int out_size, void* d_ws, size_t ws_size,
                              hipStream_t stream){
  const float* x   = (const float*)d_in[0];
  const int*   ei  = (const int*)d_in[1];
  const int*   bat = (const int*)d_in[2];
  const float* W1  = (const float*)d_in[3];
  const float* as1 = (const float*)d_in[4];
  const float* ad1 = (const float*)d_in[5];
  const float* b1  = (const float*)d_in[6];
  const float* W2  = (const float*)d_in[7];
  const float* as2 = (const float*)d_in[8];
  const float* ad2 = (const float*)d_in[9];
  const float* b2  = (const float*)d_in[10];
  const float* Wc1 = (const float*)d_in[11];
  const float* bc1 = (const float*)d_in[12];
  const float* Wc2 = (const float*)d_in[13];
  const float* bc2 = (const float*)d_in[14];
  float* out = (float*)d_out;

  const int N = in_sizes[2];
  const int E = in_sizes[1] / 2;

  float* ws = (float*)d_ws;
  size_t off = 0;
  // zero-init region (single memset): cur + gsum_part + gcnt
  int* cur    = (int*)ws;           off += (size_t)N;        // becomes deg after k_scat
  float* gsum_part = ws + off;      off += (size_t)NPART * 4096;
  float* gcnt = ws + off;           off += 128;
  const size_t zero_elems = off;
  __half* h2h = (__half*)(ws + off); off += (size_t)N * 16;  // N*32 halfs
  float* als2 = ws + off;           off += (size_t)N;
  float* ald2 = ws + off;           off += (size_t)N;
  int* csr_src= (int*)(ws + off);   off += (size_t)N * PAD;  // 128B-aligned rows

  hipMemsetAsync(d_ws, 0, zero_elems * sizeof(float), stream);

  // padded-CSR build + gcnt histogram (fused, single edge pass)
  k_scat<<<(E + 255) / 256, 256, 0, stream>>>(ei, bat, cur, csr_src, gcnt, N, E);

  // fused layer 1 (+ h2 f16 + layer-2 logits)
  k_layer1<<<(N + 31) / 32, 256, 0, stream>>>(cur, csr_src, x, W1, as1, ad1, b1,
                                              W2, as2, ad2, h2h, als2, ald2, N);

  // layer 2 gather + fused pool partials
  k_gat2<<<(N + 7) / 8, 256, 0, stream>>>(cur, csr_src, h2h, als2, ald2, b2,
                                          bat, gsum_part, N);

  // head (reduces partials)
  k_head<<<128, 64, 0, stream>>>(gsum_part, gcnt, Wc1, bc1, Wc2, bc2, out);
}